// Round 13
// baseline (19902.441 us; speedup 1.0000x reference)
//
#include <hip/hip_runtime.h>

// RadialNCA — XLA-f32 bit-replication (PASSES at absmax=0.015625) +
// temporal memoization.
// NUMERICS FROZEN on the compute path (bit-identical to R6..R12):
//   mm1: ascending-k single-acc FMA over (kh,kw,c), c fastest; + b1 add
//   tanh: Eigen/XLA fast-tanh rational (clamp 7.905..., IEEE f32 div, select)
//   mm2: ascending-n single-acc FMA; + b2; 0.5f*delta; + s0; clip
//
// R13: skip bit-static pixels. out(p,t+1) = F(patch_t(p)) with ch1/2 and
// weights constant; if patch_t(p) == patch_{t-1}(p) BITWISE then
// out(t+1) == out(t) bitwise -> copy. Pattern field is clip-saturated
// almost everywhere (out_npz: pattern channel compresses ~10:1); active
// set is a thin radial front. State = pattern-only planes, 3 rotating.

#define BATCH 8
#define HGT 256
#define WID 256
#define NHID 256
#define NPIX (BATCH * HGT * WID)   // 524288
#define ALPHA 0.5f

// ws layout (floats)
#define WS_P0  0
#define WS_P1  NPIX
#define WS_P2  (2 * NPIX)
#define WS_W1T (3 * NPIX)
#define WS_W2  (WS_W1T + 28 * NHID)

// Exact XLA/Eigen generic_fast_tanh_float
__device__ __forceinline__ float tanh_xla(float x) {
    const float cl = 7.90531110763549805f;
    float xc = fminf(fmaxf(x, -cl), cl);
    float x2 = xc * xc;
    float p = fmaf(x2, -2.76076847742355e-16f, 2.00018790482477e-13f);
    p = fmaf(x2, p, -8.60467152213735e-11f);
    p = fmaf(x2, p, 5.12229709037114e-08f);
    p = fmaf(x2, p, 1.48572235717979e-05f);
    p = fmaf(x2, p, 6.37261928875436e-04f);
    p = fmaf(x2, p, 4.89352455891786e-03f);
    p = xc * p;
    float q = fmaf(x2, 1.19825839466702e-06f, 1.18534705686654e-04f);
    q = fmaf(x2, q, 2.26843463243900e-03f);
    q = fmaf(x2, q, 4.89352518554385e-03f);
    float r = p / q;                       // IEEE f32 div (no fast-math)
    return (fabsf(x) < 0.0004f) ? x : r;
}

// w1t[n][k] = W1[k][n] for k<27; w1t[n][27] = b1[n]; then W2
__global__ __launch_bounds__(256) void nca_prep(const float* __restrict__ W1,
                                                const float* __restrict__ b1,
                                                const float* __restrict__ W2,
                                                float* __restrict__ ws) {
    int n = threadIdx.x;
    float* w1t = ws + WS_W1T;
#pragma unroll
    for (int k = 0; k < 27; ++k) w1t[n * 28 + k] = W1[k * NHID + n];
    w1t[n * 28 + 27] = b1[n];
    ws[WS_W2 + n] = W2[n];
}

// pattern plane init: P0[i] = state[i*3]
__global__ __launch_bounds__(256) void nca_init(const float* __restrict__ state,
                                                float* __restrict__ P0) {
    int i = blockIdx.x * 256 + threadIdx.x;
    if (i < NPIX) P0[i] = state[i * 3];
}

// assemble d_out from final pattern plane + constant channels
__global__ __launch_bounds__(256) void nca_final(const float* __restrict__ P,
                                                 const float* __restrict__ cstate,
                                                 float* __restrict__ out) {
    int i = blockIdx.x * 256 + threadIdx.x;
    if (i < NPIX) {
        out[i * 3]     = P[i];
        out[i * 3 + 1] = cstate[i * 3 + 1];
        out[i * 3 + 2] = cstate[i * 3 + 2];
    }
}

// one mm1 chain for pixel offset P (cols P..P+2), ascending k, c fastest
#define MM1_CHAIN(P, ACC)                                   \
    do {                                                    \
        ACC = fmaf(X[0][0 + P][0], w0.x, ACC);              \
        ACC = fmaf(X[0][0 + P][1], w0.y, ACC);              \
        ACC = fmaf(X[0][0 + P][2], w0.z, ACC);              \
        ACC = fmaf(X[0][1 + P][0], w0.w, ACC);              \
        ACC = fmaf(X[0][1 + P][1], w1.x, ACC);              \
        ACC = fmaf(X[0][1 + P][2], w1.y, ACC);              \
        ACC = fmaf(X[0][2 + P][0], w1.z, ACC);              \
        ACC = fmaf(X[0][2 + P][1], w1.w, ACC);              \
        ACC = fmaf(X[0][2 + P][2], w2v.x, ACC);             \
        ACC = fmaf(X[1][0 + P][0], w2v.y, ACC);             \
        ACC = fmaf(X[1][0 + P][1], w2v.z, ACC);             \
        ACC = fmaf(X[1][0 + P][2], w2v.w, ACC);             \
        ACC = fmaf(X[1][1 + P][0], w3.x, ACC);              \
        ACC = fmaf(X[1][1 + P][1], w3.y, ACC);              \
        ACC = fmaf(X[1][1 + P][2], w3.z, ACC);              \
        ACC = fmaf(X[1][2 + P][0], w3.w, ACC);              \
        ACC = fmaf(X[1][2 + P][1], w4.x, ACC);              \
        ACC = fmaf(X[1][2 + P][2], w4.y, ACC);              \
        ACC = fmaf(X[2][0 + P][0], w4.z, ACC);              \
        ACC = fmaf(X[2][0 + P][1], w4.w, ACC);              \
        ACC = fmaf(X[2][0 + P][2], w5.x, ACC);              \
        ACC = fmaf(X[2][1 + P][0], w5.y, ACC);              \
        ACC = fmaf(X[2][1 + P][1], w5.z, ACC);              \
        ACC = fmaf(X[2][1 + P][2], w5.w, ACC);              \
        ACC = fmaf(X[2][2 + P][0], w6.x, ACC);              \
        ACC = fmaf(X[2][2 + P][1], w6.y, ACC);              \
        ACC = fmaf(X[2][2 + P][2], w6.z, ACC);              \
        ACC = ACC + w6.w; /* + b1[n] */                     \
    } while (0)

__global__ __launch_bounds__(256)
__attribute__((amdgpu_waves_per_eu(4, 4)))
void nca_step(const float* __restrict__ Pprev,
              const float* __restrict__ Pcur,
              float* __restrict__ Pnext,
              const float* __restrict__ cstate,
              const float* __restrict__ w1t,
              const float* __restrict__ w2,
              const float* __restrict__ b2p,
              int first) {
    const int gid = blockIdx.x * 256 + threadIdx.x;   // 0..262143, 2 px each
    const int xq = gid & 127;
    const int y  = (gid >> 7) & 255;
    const int b  = gid >> 15;
    const int x0 = xq * 2;

    // pattern patch from Pcur: rows y-1..y+1, cols x0-1..x0+2
    float Pc[3][4];
#pragma unroll
    for (int r = 0; r < 3; ++r) {
        const int yy = y + r - 1;
        const bool yok = (yy >= 0) && (yy < HGT);
        const float* prow = Pcur + ((long)b * HGT + (yok ? yy : 0)) * WID;
#pragma unroll
        for (int cc = 0; cc < 4; ++cc) {
            const int xx = x0 + cc - 1;
            const bool ok = yok && (xx >= 0) && (xx < WID);
            Pc[r][cc] = ok ? prow[xx] : 0.f;
        }
    }

    const long base = ((long)b * HGT + y) * WID + x0;

    if (!first) {
        // memo check: bitwise patch equality vs previous step
        bool same = true;
#pragma unroll
        for (int r = 0; r < 3; ++r) {
            const int yy = y + r - 1;
            const bool yok = (yy >= 0) && (yy < HGT);
            const float* prow = Pprev + ((long)b * HGT + (yok ? yy : 0)) * WID;
#pragma unroll
            for (int cc = 0; cc < 4; ++cc) {
                const int xx = x0 + cc - 1;
                const bool ok = yok && (xx >= 0) && (xx < WID);
                const float pv = ok ? prow[xx] : 0.f;
                same = same && (__float_as_uint(Pc[r][cc]) == __float_as_uint(pv));
            }
        }
        if (same) {   // patch unchanged -> output bitwise equals current state
            Pnext[base]     = Pc[1][1];
            Pnext[base + 1] = Pc[1][2];
            return;
        }
    }

    // ---- full compute (frozen numerics) ----
    float X[3][4][3];
#pragma unroll
    for (int r = 0; r < 3; ++r) {
        const int yy = y + r - 1;
        const bool yok = (yy >= 0) && (yy < HGT);
        const float* crow = cstate + (((long)b * HGT + (yok ? yy : 0)) * WID) * 3;
#pragma unroll
        for (int cc = 0; cc < 4; ++cc) {
            const int xx = x0 + cc - 1;
            const bool ok = yok && (xx >= 0) && (xx < WID);
            X[r][cc][0] = Pc[r][cc];
            X[r][cc][1] = ok ? crow[xx * 3 + 1] : 0.f;
            X[r][cc][2] = ok ? crow[xx * 3 + 2] : 0.f;
        }
    }
    // Pin staged values in arch VGPRs; forbid remat/sinking.
#pragma unroll
    for (int r = 0; r < 3; ++r)
#pragma unroll
        for (int cc = 0; cc < 4; ++cc)
#pragma unroll
            for (int c = 0; c < 3; ++c)
                asm volatile("" : "+v"(X[r][cc][c]));

    const float4* __restrict__ wq = (const float4*)w1t;   // 7 float4 per n

    float delta0 = 0.f, delta1 = 0.f;

    for (int n = 0; n < NHID; ++n) {
        const float4 w0  = wq[n * 7 + 0];
        const float4 w1  = wq[n * 7 + 1];
        const float4 w2v = wq[n * 7 + 2];
        const float4 w3  = wq[n * 7 + 3];
        const float4 w4  = wq[n * 7 + 4];
        const float4 w5  = wq[n * 7 + 5];
        const float4 w6  = wq[n * 7 + 6];
        const float  w2n = w2[n];

        float a0 = 0.f, a1 = 0.f;
        MM1_CHAIN(0, a0);
        MM1_CHAIN(1, a1);
        const float h0 = tanh_xla(a0);
        const float h1 = tanh_xla(a1);
        delta0 = fmaf(h0, w2n, delta0);
        delta1 = fmaf(h1, w2n, delta1);
    }

    const float b2v = b2p[0];
    {
        const float s0 = Pc[1][1];
        const float d  = delta0 + b2v;
        const float td = ALPHA * d;
        float pat = s0 + td;
        pat = fminf(fmaxf(pat, 0.f), 1.f);
        Pnext[base] = pat;
    }
    {
        const float s0 = Pc[1][2];
        const float d  = delta1 + b2v;
        const float td = ALPHA * d;
        float pat = s0 + td;
        pat = fminf(fmaxf(pat, 0.f), 1.f);
        Pnext[base + 1] = pat;
    }
}

extern "C" void kernel_launch(void* const* d_in, const int* in_sizes, int n_in,
                              void* d_out, int out_size, void* d_ws, size_t ws_size,
                              hipStream_t stream) {
    const float* state = (const float*)d_in[0];
    const float* W1    = (const float*)d_in[1];
    const float* b1    = (const float*)d_in[2];
    const float* W2    = (const float*)d_in[3];
    const float* b2    = (const float*)d_in[4];

    float* ws  = (float*)d_ws;
    float* P[3] = {ws + WS_P0, ws + WS_P1, ws + WS_P2};
    float* w1t = ws + WS_W1T;
    float* w2c = ws + WS_W2;
    float* out = (float*)d_out;

    nca_prep<<<1, 256, 0, stream>>>(W1, b1, W2, ws);
    nca_init<<<NPIX / 256, 256, 0, stream>>>(state, P[0]);

    const int nblocks = (NPIX / 2) / 256;   // 1024

    for (int t = 0; t < 128; ++t) {
        float* prv = P[(t + 2) % 3];   // == (t-1) mod 3
        float* cur = P[t % 3];
        float* nxt = P[(t + 1) % 3];
        nca_step<<<nblocks, 256, 0, stream>>>(prv, cur, nxt, state,
                                              w1t, w2c, b2, (t == 0) ? 1 : 0);
    }
    nca_final<<<NPIX / 256, 256, 0, stream>>>(P[128 % 3], state, out);
}